// Round 1
// 612.219 us; speedup vs baseline: 1.0019x; 1.0019x over previous
//
#include <hip/hip_runtime.h>
#include <hip/hip_bf16.h>
#include <math.h>

// ---------------------------------------------------------------------------
// GRU-like cell. B=64, T=512, D=512, H=1024 (fp32).
// Round 2:
//   * GEMM: combined hi|lo LDS tiles with 128 B rows + XOR swizzle
//     (byte ^= (row&7)<<4) -> bank-conflict-free ds_read_b128. Swizzle is
//     applied on the global SOURCE addresses (global_load_lds writes
//     linearly), reads use the same XOR. LDS stays 32 KB.
//   * XCD-aware bijective block swizzle (6144 = 8*768): A panels fetched
//     once, B L2-resident per XCD.
//   * scan pipeline deepened to 16 steps/chunk (48 loads in flight) to
//     cover HBM latency at 1 wave/SIMD. Per-step math bit-identical.
// Precision: 3-term split fp16 GEMM and fp32 intermediates kept — the
// recurrence amplifies per-step input error ~1e3-1e4x (absmax 2^-8 from
// ~1e-6-level injections), so lower-precision paths are not viable.
// ---------------------------------------------------------------------------

#define M_DIM 32768   // B*T
#define K_DIM 512     // D
#define H_DIM 1024
#define N3    3072    // 3*H

typedef _Float16 half8v __attribute__((ext_vector_type(8)));
typedef _Float16 half4v __attribute__((ext_vector_type(4)));
typedef float f32x4 __attribute__((ext_vector_type(4)));

__device__ __forceinline__ f32x4 mfma16(half8v a, half8v b, f32x4 c) {
    return __builtin_amdgcn_mfma_f32_16x16x32_f16(a, b, c, 0, 0, 0);
}

__device__ __forceinline__ void load_lds16(const void* g, void* l) {
    __builtin_amdgcn_global_load_lds(
        (const __attribute__((address_space(1))) void*)g,
        (__attribute__((address_space(3))) void*)l, 16, 0, 0);
}

// ---------------------------------------------------------------------------
// Conversion: x [M,K] fp32 -> xhi/xlo fp16 (same layout), via float4.
// ---------------------------------------------------------------------------
__global__ __launch_bounds__(256) void convert_x(
    const float4* __restrict__ x4, half4v* __restrict__ hi4,
    half4v* __restrict__ lo4, int n4)
{
    int i = blockIdx.x * 256 + threadIdx.x;
    if (i >= n4) return;
    float4 v = x4[i];
    half4v h, lo;
    h.x = (_Float16)v.x; lo.x = (_Float16)(v.x - (float)h.x);
    h.y = (_Float16)v.y; lo.y = (_Float16)(v.y - (float)h.y);
    h.z = (_Float16)v.z; lo.z = (_Float16)(v.z - (float)h.z);
    h.w = (_Float16)v.w; lo.w = (_Float16)(v.w - (float)h.w);
    hi4[i] = h; lo4[i] = lo;
}

// Weights [K,1024] fp32 -> transposed hi/lo fp16 [3][1024][K].
__global__ __launch_bounds__(256) void convert_wt(
    const float* __restrict__ kz, const float* __restrict__ kr,
    const float* __restrict__ kh, _Float16* __restrict__ wth,
    _Float16* __restrict__ wtl)
{
    int gid = blockIdx.x * 256 + threadIdx.x;   // 3*1024*512
    int k = gid & (K_DIM - 1);
    int n = (gid >> 9) & (H_DIM - 1);
    int wsel = gid >> 19;                        // uniform per block
    const float* s = (wsel == 0) ? kz : ((wsel == 1) ? kr : kh);
    float v = s[(size_t)k * H_DIM + n];
    _Float16 h = (_Float16)v;
    wth[gid] = h;
    wtl[gid] = (_Float16)(v - (float)h);
}

// ---------------------------------------------------------------------------
// MFMA GEMM: C[M,3072] = A[M,512] * Bt[3072,512]^T with fp16 3-term split.
// 128x128 block tile, 4 waves each computing 64x64 (4x4 grid of 16x16x32).
// LDS tiles: 128 rows x 128 B, row = [64B hi | 64B lo], XOR-swizzled.
// ---------------------------------------------------------------------------
__global__ __launch_bounds__(256) void gemm_mfma_split(
    const _Float16* __restrict__ Ahi, const _Float16* __restrict__ Alo,
    const _Float16* __restrict__ Bthi, const _Float16* __restrict__ Btlo,
    float* __restrict__ XZ, float* __restrict__ XR, float* __restrict__ OUT)
{
    __shared__ _Float16 AT[128 * 64];   // 16 KB combined hi|lo
    __shared__ _Float16 BT[128 * 64];   // 16 KB combined hi|lo

    const int tid = threadIdx.x;
    const int w = tid >> 6, l = tid & 63;
    const int l15 = l & 15, quad = l >> 4;

    // XCD-aware bijective remap: 6144 blocks = 8 XCDs * 768. Each XCD
    // sweeps bx fast over 32 contiguous by panels (A panel reused from L2,
    // B hi+lo ~6 MB mostly L2/L3 resident per XCD).
    const int nblk = blockIdx.x;
    const int swz = (nblk & 7) * 768 + (nblk >> 3);
    const int by = swz / 24;
    const int bx = swz - by * 24;
    const long m0 = (long)by * 128;
    const long n0 = (long)bx * 128;

    f32x4 acc[4][4] = {};

    // Staging: 2048 16B slots (A 1024 | B 1024), 8 per thread. LDS dest is
    // linear in slot; the global source is inverse-swizzled so that reads
    // with byte ^ ((row&7)<<4) see a conflict-free layout.
    const _Float16* gsrc[8];
    _Float16* ldst[8];
#pragma unroll
    for (int i = 0; i < 8; ++i) {
        const int sb = w * 64 + (i & 3) * 256;    // wave-uniform slot base
        const int s  = sb + l;                    // per-lane slot 0..1023
        const int r  = s >> 3;                    // tile row
        const int o2 = ((s & 7) ^ (r & 7)) << 4;  // unswizzled byte in row
        const int part  = o2 >> 6;                // 0 = hi, 1 = lo
        const int khalf = ((o2 >> 4) & 3) * 8;    // k offset (halfs)
        const bool isB = (i >= 4);
        const long grow = (isB ? n0 : m0) + r;
        const _Float16* base =
            isB ? (part ? Btlo : Bthi) : (part ? Alo : Ahi);
        gsrc[i] = base + grow * K_DIM + khalf;
        ldst[i] = (isB ? BT : AT) + sb * 8;       // wave-uniform, linear
    }

    const int wm = (w >> 1) * 64, wn = (w & 1) * 64;

    for (int kk = 0; kk < K_DIM / 32; ++kk) {
#pragma unroll
        for (int i = 0; i < 8; ++i) {
            load_lds16(gsrc[i], ldst[i]);
            gsrc[i] += 32;
        }
        __syncthreads();

        half8v afh[4], afl[4], bfh[4], bfl[4];
#pragma unroll
        for (int mi = 0; mi < 4; ++mi) {
            const int r = wm + mi * 16 + l15;
            const int off = (quad ^ (r & 7)) * 8;      // halfs, swizzled
            afh[mi] = *(const half8v*)&AT[r * 64 + off];
            afl[mi] = *(const half8v*)&AT[r * 64 + (off ^ 32)];
        }
#pragma unroll
        for (int ni = 0; ni < 4; ++ni) {
            const int r = wn + ni * 16 + l15;
            const int off = (quad ^ (r & 7)) * 8;
            bfh[ni] = *(const half8v*)&BT[r * 64 + off];
            bfl[ni] = *(const half8v*)&BT[r * 64 + (off ^ 32)];
        }
#pragma unroll
        for (int mi = 0; mi < 4; ++mi)
#pragma unroll
            for (int ni = 0; ni < 4; ++ni) {
                acc[mi][ni] = mfma16(afh[mi], bfh[ni], acc[mi][ni]);
                acc[mi][ni] = mfma16(afh[mi], bfl[ni], acc[mi][ni]);
                acc[mi][ni] = mfma16(afl[mi], bfh[ni], acc[mi][ni]);
            }
        __syncthreads();
    }

    // Epilogue: C/D layout col=lane&15, row=quad*4+i.
    float* dst = (bx < 8) ? XZ : ((bx < 16) ? XR : OUT);
    const long nl = (long)(bx & 7) * 128 + wn + l15;
#pragma unroll
    for (int mi = 0; mi < 4; ++mi) {
        const long m = m0 + wm + mi * 16 + quad * 4;
#pragma unroll
        for (int ni = 0; ni < 4; ++ni) {
            float* p = dst + m * H_DIM + nl + ni * 16;
#pragma unroll
            for (int i = 0; i < 4; ++i)
                p[(long)i * H_DIM] = acc[mi][ni][i];
        }
    }
}

// ---------------------------------------------------------------------------
// Fallback fp32 GEMM (round 0)
// ---------------------------------------------------------------------------
#define BM 128
#define BN 128
#define BK 8
__global__ __launch_bounds__(256) void gemm_f32(
    const float* __restrict__ A, const float* __restrict__ B,
    float* __restrict__ C, int M, int N, int K)
{
    __shared__ float As[BK][BM];
    __shared__ float Bs[BK][BN];
    const int tid = threadIdx.x;
    const int bm = blockIdx.y * BM, bn = blockIdx.x * BN;
    const int tx = tid & 15, ty = tid >> 4;
    float acc[8][8];
#pragma unroll
    for (int i = 0; i < 8; i++)
#pragma unroll
        for (int j = 0; j < 8; j++) acc[i][j] = 0.f;
    const int a_row = tid >> 1, a_k = (tid & 1) * 4;
    const int b_row = tid >> 5, b_col = (tid & 31) * 4;
    const float* Aptr = A + (size_t)(bm + a_row) * K + a_k;
    const float* Bptr = B + (size_t)b_row * N + bn + b_col;
    for (int k0 = 0; k0 < K; k0 += BK) {
        float4 av = *(const float4*)(Aptr + k0);
        float4 bv = *(const float4*)(Bptr + (size_t)k0 * N);
        As[a_k + 0][a_row] = av.x; As[a_k + 1][a_row] = av.y;
        As[a_k + 2][a_row] = av.z; As[a_k + 3][a_row] = av.w;
        *(float4*)&Bs[b_row][b_col] = bv;
        __syncthreads();
#pragma unroll
        for (int kk = 0; kk < BK; kk++) {
            float4 a0 = *(const float4*)&As[kk][ty * 8];
            float4 a1 = *(const float4*)&As[kk][ty * 8 + 4];
            float4 b0 = *(const float4*)&Bs[kk][tx * 8];
            float4 b1 = *(const float4*)&Bs[kk][tx * 8 + 4];
            float a[8] = {a0.x, a0.y, a0.z, a0.w, a1.x, a1.y, a1.z, a1.w};
            float b[8] = {b0.x, b0.y, b0.z, b0.w, b1.x, b1.y, b1.z, b1.w};
#pragma unroll
            for (int i = 0; i < 8; i++)
#pragma unroll
                for (int j = 0; j < 8; j++)
                    acc[i][j] = fmaf(a[i], b[j], acc[i][j]);
        }
        __syncthreads();
    }
    float* Cptr = C + (size_t)(bm + ty * 8) * N + bn + tx * 8;
#pragma unroll
    for (int i = 0; i < 8; i++) {
        float4 c0 = {acc[i][0], acc[i][1], acc[i][2], acc[i][3]};
        float4 c1 = {acc[i][4], acc[i][5], acc[i][6], acc[i][7]};
        *(float4*)(Cptr + (size_t)i * N)     = c0;
        *(float4*)(Cptr + (size_t)i * N + 4) = c1;
    }
}

// ---------------------------------------------------------------------------
// Scan, 16-deep software pipeline (48 loads in flight per wave).
// OUT holds xh on entry, h_t on exit. Per-step math identical to round 1.
// ---------------------------------------------------------------------------
__device__ __forceinline__ float fast_tanh(float x) {
    return 1.0f - 2.0f / (__expf(2.0f * x) + 1.0f);
}
__device__ __forceinline__ float fast_sigmoid(float x) {
    return 1.0f / (1.0f + __expf(-x));
}

__global__ __launch_bounds__(256) void scan_kernel(
    const float* __restrict__ XZ, const float* __restrict__ XR,
    float* __restrict__ OUT,
    const float* __restrict__ mz, const float* __restrict__ mr,
    const float* __restrict__ br, const float* __restrict__ bz)
{
    const int gid = blockIdx.x * blockDim.x + threadIdx.x;
    const int b = gid >> 10;          // H=1024
    const int h = gid & (H_DIM - 1);

    const float mzv = mz[h], mrv = mr[h], brv = br[h], bzv = bz[h];
    float hs = 0.f;
    size_t idx = (size_t)b * 512 * H_DIM + h;

    float cz[16], cr[16], ch[16];
#pragma unroll
    for (int j = 0; j < 16; ++j) {
        cz[j] = XZ[idx + (size_t)j * H_DIM];
        cr[j] = XR[idx + (size_t)j * H_DIM];
        ch[j] = OUT[idx + (size_t)j * H_DIM];
    }
    for (int t0 = 0; t0 < 512; t0 += 16) {
        float nz[16], nr[16], nh[16];
        const bool more = (t0 + 16) < 512;
        const size_t nidx = idx + 16ul * H_DIM;
        if (more) {
#pragma unroll
            for (int j = 0; j < 16; ++j) {
                nz[j] = XZ[nidx + (size_t)j * H_DIM];
                nr[j] = XR[nidx + (size_t)j * H_DIM];
                nh[j] = OUT[nidx + (size_t)j * H_DIM];
            }
        }
#pragma unroll
        for (int j = 0; j < 16; ++j) {
            const float r = fast_tanh(fmaf(hs, mrv, cr[j]) + brv) + 1.0f;
            const float z = fast_sigmoid(fmaf(hs, mzv, cz[j]) + bzv);
            const float hn = fmaf(z, hs, (1.0f - z) * fast_tanh(fmaf(r, hs, ch[j])));
            OUT[idx + (size_t)j * H_DIM] = hn;
            hs = hn;
        }
        idx = nidx;
        if (more) {
#pragma unroll
            for (int j = 0; j < 16; ++j) { cz[j] = nz[j]; cr[j] = nr[j]; ch[j] = nh[j]; }
        }
    }
}

// ---------------------------------------------------------------------------
extern "C" void kernel_launch(void* const* d_in, const int* in_sizes, int n_in,
                              void* d_out, int out_size, void* d_ws, size_t ws_size,
                              hipStream_t stream) {
    const float* x  = (const float*)d_in[0];
    const float* kz = (const float*)d_in[1];
    const float* kr = (const float*)d_in[2];
    const float* kh = (const float*)d_in[3];
    const float* mz = (const float*)d_in[4];
    const float* mr = (const float*)d_in[5];
    const float* br = (const float*)d_in[6];
    const float* bz = (const float*)d_in[7];
    float* out = (float*)d_out;

    char* ws = (char*)d_ws;
    float* XZ = (float*)ws;                              // 128 MiB
    float* XR = (float*)(ws + 134217728ul);              // 128 MiB
    _Float16* XHI = (_Float16*)(ws + 268435456ul);       // 32 MiB
    _Float16* XLO = (_Float16*)(ws + 301989888ul);       // 32 MiB
    _Float16* WTH = (_Float16*)(ws + 335544320ul);       // 3 MiB
    _Float16* WTL = (_Float16*)(ws + 338690048ul);       // 3 MiB
    const size_t need = 341835776ul;

    if (ws_size >= need) {
        int n4 = M_DIM * K_DIM / 4;                      // 4.19M
        convert_x<<<n4 / 256, 256, 0, stream>>>(
            (const float4*)x, (half4v*)XHI, (half4v*)XLO, n4);
        convert_wt<<<(3 * H_DIM * K_DIM) / 256, 256, 0, stream>>>(
            kz, kr, kh, WTH, WTL);
        gemm_mfma_split<<<6144, 256, 0, stream>>>(
            XHI, XLO, WTH, WTL, XZ, XR, out);
    } else {
        dim3 grid(H_DIM / BN, M_DIM / BM);
        gemm_f32<<<grid, 256, 0, stream>>>(x, kz, XZ,  M_DIM, H_DIM, K_DIM);
        gemm_f32<<<grid, 256, 0, stream>>>(x, kr, XR,  M_DIM, H_DIM, K_DIM);
        gemm_f32<<<grid, 256, 0, stream>>>(x, kh, out, M_DIM, H_DIM, K_DIM);
    }

    scan_kernel<<<(64 * H_DIM) / 256, 256, 0, stream>>>(
        XZ, XR, out, mz, mr, br, bz);
}

// Round 2
// 609.268 us; speedup vs baseline: 1.0067x; 1.0048x over previous
//
#include <hip/hip_runtime.h>
#include <hip/hip_bf16.h>
#include <math.h>

// ---------------------------------------------------------------------------
// GRU-like cell. B=64, T=512, D=512, H=1024 (fp32).
// Round 3:
//   * GEMM rebuilt on the 256x256-tile, 8-wave, double-buffered phased
//     schedule (T3+T4+T5): raw s_barrier + manual waitcnts, staging loads
//     issued one K-step ahead, vmcnt(0) only once per K-step (~96 MFMAs
//     after issue), s_setprio(1) around MFMA clusters. 128 KiB LDS,
//     1 block/CU. hi|lo split rows + XOR swizzle carried from round 1/2
//     (verified correct; conflict-free reads only pay off in this regime).
//   * 2 MFMA sub-phases per K-step (mi 0-3 / mi 4-7), B frags held in
//     registers across both.
// Precision: 3-term fp16 split GEMM and fp32 scan unchanged (recurrence
// amplifies input error ~1e3-1e4x; absmax currently 2^-8).
// ---------------------------------------------------------------------------

#define M_DIM 32768   // B*T
#define K_DIM 512     // D
#define H_DIM 1024
#define N3    3072    // 3*H

typedef _Float16 half8v __attribute__((ext_vector_type(8)));
typedef _Float16 half4v __attribute__((ext_vector_type(4)));
typedef float f32x4 __attribute__((ext_vector_type(4)));

__device__ __forceinline__ f32x4 mfma16(half8v a, half8v b, f32x4 c) {
    return __builtin_amdgcn_mfma_f32_16x16x32_f16(a, b, c, 0, 0, 0);
}

__device__ __forceinline__ void load_lds16(const void* g, void* l) {
    __builtin_amdgcn_global_load_lds(
        (const __attribute__((address_space(1))) void*)g,
        (__attribute__((address_space(3))) void*)l, 16, 0, 0);
}

// ---------------------------------------------------------------------------
// Conversion: x [M,K] fp32 -> xhi/xlo fp16 (same layout), via float4.
// ---------------------------------------------------------------------------
__global__ __launch_bounds__(256) void convert_x(
    const float4* __restrict__ x4, half4v* __restrict__ hi4,
    half4v* __restrict__ lo4, int n4)
{
    int i = blockIdx.x * 256 + threadIdx.x;
    if (i >= n4) return;
    float4 v = x4[i];
    half4v h, lo;
    h.x = (_Float16)v.x; lo.x = (_Float16)(v.x - (float)h.x);
    h.y = (_Float16)v.y; lo.y = (_Float16)(v.y - (float)h.y);
    h.z = (_Float16)v.z; lo.z = (_Float16)(v.z - (float)h.z);
    h.w = (_Float16)v.w; lo.w = (_Float16)(v.w - (float)h.w);
    hi4[i] = h; lo4[i] = lo;
}

// Weights [K,1024] fp32 -> transposed hi/lo fp16 [3][1024][K].
__global__ __launch_bounds__(256) void convert_wt(
    const float* __restrict__ kz, const float* __restrict__ kr,
    const float* __restrict__ kh, _Float16* __restrict__ wth,
    _Float16* __restrict__ wtl)
{
    int gid = blockIdx.x * 256 + threadIdx.x;   // 3*1024*512
    int k = gid & (K_DIM - 1);
    int n = (gid >> 9) & (H_DIM - 1);
    int wsel = gid >> 19;                        // uniform per block
    const float* s = (wsel == 0) ? kz : ((wsel == 1) ? kr : kh);
    float v = s[(size_t)k * H_DIM + n];
    _Float16 h = (_Float16)v;
    wth[gid] = h;
    wtl[gid] = (_Float16)(v - (float)h);
}

// ---------------------------------------------------------------------------
// MFMA GEMM: C[M,3072] = A[M,512] * Bt[3072,512]^T, fp16 3-term split.
// 256x256 block tile, 512 threads (8 waves, 2x4), per-wave 128x64 output.
// BK=32. LDS: 2 x (A 32KB + B 32KB) = 128 KiB, rows = [64B hi | 64B lo],
// XOR-swizzled (inverse-swizzled global source, swizzled ds_read).
// Phased schedule per K-step:
//   phase 0: ds_read B(all)+A(mi0-3); issue 4 A-stages(next); barrier;
//            lgkmcnt(0); setprio1; 48 MFMA; setprio0; barrier
//   phase 1: ds_read A(mi4-7); issue 4 B-stages(next); barrier;
//            lgkmcnt(0); setprio1; 48 MFMA; setprio0; vmcnt(0); barrier
// ---------------------------------------------------------------------------
__global__ __launch_bounds__(512, 2) void gemm_mfma_split(
    const _Float16* __restrict__ Ahi, const _Float16* __restrict__ Alo,
    const _Float16* __restrict__ Bthi, const _Float16* __restrict__ Btlo,
    float* __restrict__ XZ, float* __restrict__ XR, float* __restrict__ OUT)
{
    __shared__ _Float16 AT[2][256 * 64];   // 32 KB per buffer
    __shared__ _Float16 BT[2][256 * 64];

    const int tid = threadIdx.x;
    const int w = tid >> 6, l = tid & 63;
    const int l15 = l & 15, quad = l >> 4;
    const int wr = w >> 2;          // 0..1  (M groups of 128)
    const int wc = w & 3;           // 0..3  (N groups of 64)

    // XCD-aware bijective remap: 1536 blocks = 8 XCDs * 192.
    // Each XCD sweeps bx fast over 16 contiguous by panels.
    const int nblk = blockIdx.x;
    const int swz = (nblk & 7) * 192 + (nblk >> 3);
    const int by = swz / 12;
    const int bx = swz - by * 12;
    const long m0 = (long)by * 256;
    const long n0 = (long)bx * 256;

    f32x4 acc[8][4] = {};

    // Staging: per matrix 2048 16B slots per K-step; 4 per thread.
    // slot s -> row r=s>>3, unit u=s&7; source byte within row =
    // (u ^ (r&7))*16 (inverse swizzle); LDS dest linear at s*16.
    const _Float16* gA[4]; const _Float16* gB[4];
    int lofs[4];
#pragma unroll
    for (int i = 0; i < 4; ++i) {
        const int s = i * 512 + tid;
        const int r = s >> 3;
        const int o2 = ((s & 7) ^ (r & 7)) << 4;
        const int part  = o2 >> 6;                 // 0 = hi, 1 = lo
        const int khalf = ((o2 >> 4) & 3) * 8;
        gA[i] = (part ? Alo : Ahi) + (m0 + r) * K_DIM + khalf;
        gB[i] = (part ? Btlo : Bthi) + (n0 + r) * K_DIM + khalf;
        lofs[i] = (i * 512 + (w << 6)) * 8;        // wave-uniform halfs
    }

    // Prologue: stage K-step 0 into buffer 0.
#pragma unroll
    for (int i = 0; i < 4; ++i) { load_lds16(gA[i], &AT[0][lofs[i]]); gA[i] += 32; }
#pragma unroll
    for (int i = 0; i < 4; ++i) { load_lds16(gB[i], &BT[0][lofs[i]]); gB[i] += 32; }
    asm volatile("s_waitcnt vmcnt(0)" ::: "memory");
    __builtin_amdgcn_s_barrier();

    int cur = 0;
    for (int t = 0; t < 16; ++t) {
        const bool pf = (t + 1) < 16;
        const _Float16* at = &AT[cur][0];
        const _Float16* bt = &BT[cur][0];
        _Float16* an = &AT[cur ^ 1][0];
        _Float16* bn = &BT[cur ^ 1][0];

        // ---------------- phase 0 ----------------
        half8v bfh[4], bfl[4], afh[4], afl[4];
#pragma unroll
        for (int ni = 0; ni < 4; ++ni) {
            const int r = wc * 64 + ni * 16 + l15;
            const int off = (quad ^ (r & 7)) * 8;
            bfh[ni] = *(const half8v*)&bt[r * 64 + off];
            bfl[ni] = *(const half8v*)&bt[r * 64 + (off ^ 32)];
        }
#pragma unroll
        for (int mi = 0; mi < 4; ++mi) {
            const int r = wr * 128 + mi * 16 + l15;
            const int off = (quad ^ (r & 7)) * 8;
            afh[mi] = *(const half8v*)&at[r * 64 + off];
            afl[mi] = *(const half8v*)&at[r * 64 + (off ^ 32)];
        }
        if (pf) {
#pragma unroll
            for (int i = 0; i < 4; ++i) { load_lds16(gA[i], an + lofs[i]); gA[i] += 32; }
        }
        __builtin_amdgcn_s_barrier();
        asm volatile("s_waitcnt lgkmcnt(0)" ::: "memory");
        __builtin_amdgcn_sched_barrier(0);
        __builtin_amdgcn_s_setprio(1);
#pragma unroll
        for (int mi = 0; mi < 4; ++mi)
#pragma unroll
            for (int ni = 0; ni < 4; ++ni)
                acc[mi][ni] = mfma16(afh[mi], bfh[ni], acc[mi][ni]);
#pragma unroll
        for (int mi = 0; mi < 4; ++mi)
#pragma unroll
            for (int ni = 0; ni < 4; ++ni)
                acc[mi][ni] = mfma16(afh[mi], bfl[ni], acc[mi][ni]);
#pragma unroll
        for (int mi = 0; mi < 4; ++mi)
#pragma unroll
            for (int ni = 0; ni < 4; ++ni)
                acc[mi][ni] = mfma16(afl[mi], bfh[ni], acc[mi][ni]);
        __builtin_amdgcn_s_setprio(0);
        __builtin_amdgcn_s_barrier();

        // ---------------- phase 1 ----------------
        half8v afh2[4], afl2[4];
#pragma unroll
        for (int mi = 0; mi < 4; ++mi) {
            const int r = wr * 128 + 64 + mi * 16 + l15;
            const int off = (quad ^ (r & 7)) * 8;
            afh2[mi] = *(const half8v*)&at[r * 64 + off];
            afl2[mi] = *(const half8v*)&at[r * 64 + (off ^ 32)];
        }
        if (pf) {
#pragma unroll
            for (int i = 0; i < 4; ++i) { load_lds16(gB[i], bn + lofs[i]); gB[i] += 32; }
        }
        __builtin_amdgcn_s_barrier();
        asm volatile("s_waitcnt lgkmcnt(0)" ::: "memory");
        __builtin_amdgcn_sched_barrier(0);
        __builtin_amdgcn_s_setprio(1);
#pragma unroll
        for (int mi = 0; mi < 4; ++mi)
#pragma unroll
            for (int ni = 0; ni < 4; ++ni)
                acc[4 + mi][ni] = mfma16(afh2[mi], bfh[ni], acc[4 + mi][ni]);
#pragma unroll
        for (int mi = 0; mi < 4; ++mi)
#pragma unroll
            for (int ni = 0; ni < 4; ++ni)
                acc[4 + mi][ni] = mfma16(afh2[mi], bfl[ni], acc[4 + mi][ni]);
#pragma unroll
        for (int mi = 0; mi < 4; ++mi)
#pragma unroll
            for (int ni = 0; ni < 4; ++ni)
                acc[4 + mi][ni] = mfma16(afl2[mi], bfh[ni], acc[4 + mi][ni]);
        __builtin_amdgcn_s_setprio(0);
        // Drain next-step staging (issued >=48 MFMAs ago) once per K-step.
        asm volatile("s_waitcnt vmcnt(0)" ::: "memory");
        __builtin_amdgcn_s_barrier();
        cur ^= 1;
    }

    // Epilogue: C/D layout col=lane&15, row=quad*4+i. 256-col tile maps to
    // one of XZ|XR|OUT (1024 cols each; bx&3 selects the 256-col slice).
    float* dst = (bx < 4) ? XZ : ((bx < 8) ? XR : OUT);
    const long nl = (long)(bx & 3) * 256 + wc * 64 + l15;
#pragma unroll
    for (int mi = 0; mi < 8; ++mi) {
        const long m = m0 + wr * 128 + mi * 16 + quad * 4;
#pragma unroll
        for (int ni = 0; ni < 4; ++ni) {
            float* p = dst + m * H_DIM + nl + ni * 16;
#pragma unroll
            for (int i = 0; i < 4; ++i)
                p[(long)i * H_DIM] = acc[mi][ni][i];
        }
    }
}

// ---------------------------------------------------------------------------
// Fallback fp32 GEMM (round 0)
// ---------------------------------------------------------------------------
#define BM 128
#define BN 128
#define BK 8
__global__ __launch_bounds__(256) void gemm_f32(
    const float* __restrict__ A, const float* __restrict__ B,
    float* __restrict__ C, int M, int N, int K)
{
    __shared__ float As[BK][BM];
    __shared__ float Bs[BK][BN];
    const int tid = threadIdx.x;
    const int bm = blockIdx.y * BM, bn = blockIdx.x * BN;
    const int tx = tid & 15, ty = tid >> 4;
    float acc[8][8];
#pragma unroll
    for (int i = 0; i < 8; i++)
#pragma unroll
        for (int j = 0; j < 8; j++) acc[i][j] = 0.f;
    const int a_row = tid >> 1, a_k = (tid & 1) * 4;
    const int b_row = tid >> 5, b_col = (tid & 31) * 4;
    const float* Aptr = A + (size_t)(bm + a_row) * K + a_k;
    const float* Bptr = B + (size_t)b_row * N + bn + b_col;
    for (int k0 = 0; k0 < K; k0 += BK) {
        float4 av = *(const float4*)(Aptr + k0);
        float4 bv = *(const float4*)(Bptr + (size_t)k0 * N);
        As[a_k + 0][a_row] = av.x; As[a_k + 1][a_row] = av.y;
        As[a_k + 2][a_row] = av.z; As[a_k + 3][a_row] = av.w;
        *(float4*)&Bs[b_row][b_col] = bv;
        __syncthreads();
#pragma unroll
        for (int kk = 0; kk < BK; kk++) {
            float4 a0 = *(const float4*)&As[kk][ty * 8];
            float4 a1 = *(const float4*)&As[kk][ty * 8 + 4];
            float4 b0 = *(const float4*)&Bs[kk][tx * 8];
            float4 b1 = *(const float4*)&Bs[kk][tx * 8 + 4];
            float a[8] = {a0.x, a0.y, a0.z, a0.w, a1.x, a1.y, a1.z, a1.w};
            float b[8] = {b0.x, b0.y, b0.z, b0.w, b1.x, b1.y, b1.z, b1.w};
#pragma unroll
            for (int i = 0; i < 8; i++)
#pragma unroll
                for (int j = 0; j < 8; j++)
                    acc[i][j] = fmaf(a[i], b[j], acc[i][j]);
        }
        __syncthreads();
    }
    float* Cptr = C + (size_t)(bm + ty * 8) * N + bn + tx * 8;
#pragma unroll
    for (int i = 0; i < 8; i++) {
        float4 c0 = {acc[i][0], acc[i][1], acc[i][2], acc[i][3]};
        float4 c1 = {acc[i][4], acc[i][5], acc[i][6], acc[i][7]};
        *(float4*)(Cptr + (size_t)i * N)     = c0;
        *(float4*)(Cptr + (size_t)i * N + 4) = c1;
    }
}

// ---------------------------------------------------------------------------
// Scan, 16-deep software pipeline (48 loads in flight per wave).
// OUT holds xh on entry, h_t on exit.
// ---------------------------------------------------------------------------
__device__ __forceinline__ float fast_tanh(float x) {
    return 1.0f - 2.0f / (__expf(2.0f * x) + 1.0f);
}
__device__ __forceinline__ float fast_sigmoid(float x) {
    return 1.0f / (1.0f + __expf(-x));
}

__global__ __launch_bounds__(256) void scan_kernel(
    const float* __restrict__ XZ, const float* __restrict__ XR,
    float* __restrict__ OUT,
    const float* __restrict__ mz, const float* __restrict__ mr,
    const float* __restrict__ br, const float* __restrict__ bz)
{
    const int gid = blockIdx.x * blockDim.x + threadIdx.x;
    const int b = gid >> 10;          // H=1024
    const int h = gid & (H_DIM - 1);

    const float mzv = mz[h], mrv = mr[h], brv = br[h], bzv = bz[h];
    float hs = 0.f;
    size_t idx = (size_t)b * 512 * H_DIM + h;

    float cz[16], cr[16], ch[16];
#pragma unroll
    for (int j = 0; j < 16; ++j) {
        cz[j] = XZ[idx + (size_t)j * H_DIM];
        cr[j] = XR[idx + (size_t)j * H_DIM];
        ch[j] = OUT[idx + (size_t)j * H_DIM];
    }
    for (int t0 = 0; t0 < 512; t0 += 16) {
        float nz[16], nr[16], nh[16];
        const bool more = (t0 + 16) < 512;
        const size_t nidx = idx + 16ul * H_DIM;
        if (more) {
#pragma unroll
            for (int j = 0; j < 16; ++j) {
                nz[j] = XZ[nidx + (size_t)j * H_DIM];
                nr[j] = XR[nidx + (size_t)j * H_DIM];
                nh[j] = OUT[nidx + (size_t)j * H_DIM];
            }
        }
#pragma unroll
        for (int j = 0; j < 16; ++j) {
            const float r = fast_tanh(fmaf(hs, mrv, cr[j]) + brv) + 1.0f;
            const float z = fast_sigmoid(fmaf(hs, mzv, cz[j]) + bzv);
            const float hn = fmaf(z, hs, (1.0f - z) * fast_tanh(fmaf(r, hs, ch[j])));
            OUT[idx + (size_t)j * H_DIM] = hn;
            hs = hn;
        }
        idx = nidx;
        if (more) {
#pragma unroll
            for (int j = 0; j < 16; ++j) { cz[j] = nz[j]; cr[j] = nr[j]; ch[j] = nh[j]; }
        }
    }
}

// ---------------------------------------------------------------------------
extern "C" void kernel_launch(void* const* d_in, const int* in_sizes, int n_in,
                              void* d_out, int out_size, void* d_ws, size_t ws_size,
                              hipStream_t stream) {
    const float* x  = (const float*)d_in[0];
    const float* kz = (const float*)d_in[1];
    const float* kr = (const float*)d_in[2];
    const float* kh = (const float*)d_in[3];
    const float* mz = (const float*)d_in[4];
    const float* mr = (const float*)d_in[5];
    const float* br = (const float*)d_in[6];
    const float* bz = (const float*)d_in[7];
    float* out = (float*)d_out;

    char* ws = (char*)d_ws;
    float* XZ = (float*)ws;                              // 128 MiB
    float* XR = (float*)(ws + 134217728ul);              // 128 MiB
    _Float16* XHI = (_Float16*)(ws + 268435456ul);       // 32 MiB
    _Float16* XLO = (_Float16*)(ws + 301989888ul);       // 32 MiB
    _Float16* WTH = (_Float16*)(ws + 335544320ul);       // 3 MiB
    _Float16* WTL = (_Float16*)(ws + 338690048ul);       // 3 MiB
    const size_t need = 341835776ul;

    if (ws_size >= need) {
        int n4 = M_DIM * K_DIM / 4;                      // 4.19M
        convert_x<<<n4 / 256, 256, 0, stream>>>(
            (const float4*)x, (half4v*)XHI, (half4v*)XLO, n4);
        convert_wt<<<(3 * H_DIM * K_DIM) / 256, 256, 0, stream>>>(
            kz, kr, kh, WTH, WTL);
        gemm_mfma_split<<<1536, 512, 0, stream>>>(
            XHI, XLO, WTH, WTL, XZ, XR, out);
    } else {
        dim3 grid(H_DIM / BN, M_DIM / BM);
        gemm_f32<<<grid, 256, 0, stream>>>(x, kz, XZ,  M_DIM, H_DIM, K_DIM);
        gemm_f32<<<grid, 256, 0, stream>>>(x, kr, XR,  M_DIM, H_DIM, K_DIM);
        gemm_f32<<<grid, 256, 0, stream>>>(x, kh, out, M_DIM, H_DIM, K_DIM);
    }

    scan_kernel<<<(64 * H_DIM) / 256, 256, 0, stream>>>(
        XZ, XR, out, mz, mr, br, bz);
}

// Round 3
// 586.754 us; speedup vs baseline: 1.0453x; 1.0384x over previous
//
#include <hip/hip_runtime.h>
#include <hip/hip_bf16.h>
#include <math.h>

// ---------------------------------------------------------------------------
// GRU-like cell. B=64, T=512, D=512, H=1024 (fp32).
// Round 4:
//   * GEMM: single-barrier-per-K-step schedule. Staging for step t+1 issued
//     at the START of step t (into the non-read buffer -> no hazard, cover =
//     full step >> HBM latency), all ds_reads + 96 MFMAs in one region with
//     NO manual lgkm waits / sched_barriers -> compiler interleaves reads
//     under MFMAs (its lgkm scheduling is near-optimal; round-2's pins
//     forced serial read->MFMA phases = 41% MfmaUtil).
//   * Scan: the 3 IEEE fdivs per step (~50-60cy each, all on the serial
//     h-chain; no fast-math in harness) replaced by v_rcp + 1 Newton step;
//     biases and 2x factors folded off the critical chain (sigmoid forms:
//     r=2*sig(2q), tanh(y)=2*sig(2y)-1). Chain ~290 -> ~110 cy/step.
// Precision: 3-term fp16 split GEMM unchanged; NR-refined rcp ~= IEEE div.
// ---------------------------------------------------------------------------

#define M_DIM 32768   // B*T
#define K_DIM 512     // D
#define H_DIM 1024
#define N3    3072    // 3*H

typedef _Float16 half8v __attribute__((ext_vector_type(8)));
typedef _Float16 half4v __attribute__((ext_vector_type(4)));
typedef float f32x4 __attribute__((ext_vector_type(4)));

__device__ __forceinline__ f32x4 mfma16(half8v a, half8v b, f32x4 c) {
    return __builtin_amdgcn_mfma_f32_16x16x32_f16(a, b, c, 0, 0, 0);
}

__device__ __forceinline__ void load_lds16(const void* g, void* l) {
    __builtin_amdgcn_global_load_lds(
        (const __attribute__((address_space(1))) void*)g,
        (__attribute__((address_space(3))) void*)l, 16, 0, 0);
}

// ---------------------------------------------------------------------------
// Conversion: x [M,K] fp32 -> xhi/xlo fp16 (same layout), via float4.
// ---------------------------------------------------------------------------
__global__ __launch_bounds__(256) void convert_x(
    const float4* __restrict__ x4, half4v* __restrict__ hi4,
    half4v* __restrict__ lo4, int n4)
{
    int i = blockIdx.x * 256 + threadIdx.x;
    if (i >= n4) return;
    float4 v = x4[i];
    half4v h, lo;
    h.x = (_Float16)v.x; lo.x = (_Float16)(v.x - (float)h.x);
    h.y = (_Float16)v.y; lo.y = (_Float16)(v.y - (float)h.y);
    h.z = (_Float16)v.z; lo.z = (_Float16)(v.z - (float)h.z);
    h.w = (_Float16)v.w; lo.w = (_Float16)(v.w - (float)h.w);
    hi4[i] = h; lo4[i] = lo;
}

// Weights [K,1024] fp32 -> transposed hi/lo fp16 [3][1024][K].
__global__ __launch_bounds__(256) void convert_wt(
    const float* __restrict__ kz, const float* __restrict__ kr,
    const float* __restrict__ kh, _Float16* __restrict__ wth,
    _Float16* __restrict__ wtl)
{
    int gid = blockIdx.x * 256 + threadIdx.x;   // 3*1024*512
    int k = gid & (K_DIM - 1);
    int n = (gid >> 9) & (H_DIM - 1);
    int wsel = gid >> 19;                        // uniform per block
    const float* s = (wsel == 0) ? kz : ((wsel == 1) ? kr : kh);
    float v = s[(size_t)k * H_DIM + n];
    _Float16 h = (_Float16)v;
    wth[gid] = h;
    wtl[gid] = (_Float16)(v - (float)h);
}

// ---------------------------------------------------------------------------
// MFMA GEMM: C[M,3072] = A[M,512] * Bt[3072,512]^T, fp16 3-term split.
// 256x256 block tile, 512 threads (8 waves, 2x4), per-wave 128x64 output.
// BK=32. LDS: 2 x (A 32KB + B 32KB) = 128 KiB, rows = [64B hi | 64B lo],
// XOR-swizzled (inverse-swizzled global source, swizzled ds_read).
// Per K-step: [issue 8 staging loads for t+1 -> other buffer]
//             [24 ds_read + 96 MFMA, compiler-scheduled lgkm interleave]
//             [vmcnt(0): drains t+1 staging, issued a full step ago]
//             [one s_barrier]
// ---------------------------------------------------------------------------
__global__ __launch_bounds__(512, 2) void gemm_mfma_split(
    const _Float16* __restrict__ Ahi, const _Float16* __restrict__ Alo,
    const _Float16* __restrict__ Bthi, const _Float16* __restrict__ Btlo,
    float* __restrict__ XZ, float* __restrict__ XR, float* __restrict__ OUT)
{
    __shared__ _Float16 AT[2][256 * 64];   // 32 KB per buffer
    __shared__ _Float16 BT[2][256 * 64];

    const int tid = threadIdx.x;
    const int w = tid >> 6, l = tid & 63;
    const int l15 = l & 15, quad = l >> 4;
    const int wr = w >> 2;          // 0..1  (M groups of 128)
    const int wc = w & 3;           // 0..3  (N groups of 64)

    // XCD-aware bijective remap: 1536 blocks = 8 XCDs * 192.
    const int nblk = blockIdx.x;
    const int swz = (nblk & 7) * 192 + (nblk >> 3);
    const int by = swz / 12;
    const int bx = swz - by * 12;
    const long m0 = (long)by * 256;
    const long n0 = (long)bx * 256;

    f32x4 acc[8][4] = {};

    // Staging: per matrix 2048 16B slots per K-step; 4 per thread.
    // slot s -> row r=s>>3, unit u=s&7; source byte within row =
    // (u ^ (r&7))*16 (inverse swizzle); LDS dest linear at s*16.
    const _Float16* gA[4]; const _Float16* gB[4];
    int lofs[4];
#pragma unroll
    for (int i = 0; i < 4; ++i) {
        const int s = i * 512 + tid;
        const int r = s >> 3;
        const int o2 = ((s & 7) ^ (r & 7)) << 4;
        const int part  = o2 >> 6;                 // 0 = hi, 1 = lo
        const int khalf = ((o2 >> 4) & 3) * 8;
        gA[i] = (part ? Alo : Ahi) + (m0 + r) * K_DIM + khalf;
        gB[i] = (part ? Btlo : Bthi) + (n0 + r) * K_DIM + khalf;
        lofs[i] = (i * 512 + (w << 6)) * 8;        // wave-uniform halfs
    }

    // Prologue: stage K-step 0 into buffer 0.
#pragma unroll
    for (int i = 0; i < 4; ++i) { load_lds16(gA[i], &AT[0][lofs[i]]); gA[i] += 32; }
#pragma unroll
    for (int i = 0; i < 4; ++i) { load_lds16(gB[i], &BT[0][lofs[i]]); gB[i] += 32; }
    asm volatile("s_waitcnt vmcnt(0)" ::: "memory");
    __builtin_amdgcn_s_barrier();

    for (int t = 0; t < 16; ++t) {
        const int cur = t & 1;
        const _Float16* at = &AT[cur][0];
        const _Float16* bt = &BT[cur][0];

        // Issue staging for t+1 into the buffer NOT read this step.
        // Safe: that buffer's step-(t-1) reads were consumed by step-(t-1)
        // MFMAs before the end-of-step barrier.
        if (t + 1 < 16) {
            _Float16* an = &AT[cur ^ 1][0];
            _Float16* bn = &BT[cur ^ 1][0];
#pragma unroll
            for (int i = 0; i < 4; ++i) { load_lds16(gA[i], an + lofs[i]); gA[i] += 32; }
#pragma unroll
            for (int i = 0; i < 4; ++i) { load_lds16(gB[i], bn + lofs[i]); gB[i] += 32; }
        }

        // Fragment reads + MFMA clusters; no manual lgkm waits -> compiler
        // interleaves ds_read returns under MFMA issue.
        half8v bfh[4], bfl[4];
#pragma unroll
        for (int ni = 0; ni < 4; ++ni) {
            const int r = wc * 64 + ni * 16 + l15;
            const int off = (quad ^ (r & 7)) * 8;
            bfh[ni] = *(const half8v*)&bt[r * 64 + off];
            bfl[ni] = *(const half8v*)&bt[r * 64 + (off ^ 32)];
        }
        half8v afh[4], afl[4];
#pragma unroll
        for (int mi = 0; mi < 4; ++mi) {
            const int r = wr * 128 + mi * 16 + l15;
            const int off = (quad ^ (r & 7)) * 8;
            afh[mi] = *(const half8v*)&at[r * 64 + off];
            afl[mi] = *(const half8v*)&at[r * 64 + (off ^ 32)];
        }
        __builtin_amdgcn_s_setprio(1);
#pragma unroll
        for (int mi = 0; mi < 4; ++mi)
#pragma unroll
            for (int ni = 0; ni < 4; ++ni)
                acc[mi][ni] = mfma16(afh[mi], bfh[ni], acc[mi][ni]);
#pragma unroll
        for (int mi = 0; mi < 4; ++mi)
#pragma unroll
            for (int ni = 0; ni < 4; ++ni)
                acc[mi][ni] = mfma16(afh[mi], bfl[ni], acc[mi][ni]);
#pragma unroll
        for (int mi = 0; mi < 4; ++mi)
#pragma unroll
            for (int ni = 0; ni < 4; ++ni)
                acc[mi][ni] = mfma16(afl[mi], bfh[ni], acc[mi][ni]);
        __builtin_amdgcn_s_setprio(0);

        half8v afh2[4], afl2[4];
#pragma unroll
        for (int mi = 0; mi < 4; ++mi) {
            const int r = wr * 128 + 64 + mi * 16 + l15;
            const int off = (quad ^ (r & 7)) * 8;
            afh2[mi] = *(const half8v*)&at[r * 64 + off];
            afl2[mi] = *(const half8v*)&at[r * 64 + (off ^ 32)];
        }
        __builtin_amdgcn_s_setprio(1);
#pragma unroll
        for (int mi = 0; mi < 4; ++mi)
#pragma unroll
            for (int ni = 0; ni < 4; ++ni)
                acc[4 + mi][ni] = mfma16(afh2[mi], bfh[ni], acc[4 + mi][ni]);
#pragma unroll
        for (int mi = 0; mi < 4; ++mi)
#pragma unroll
            for (int ni = 0; ni < 4; ++ni)
                acc[4 + mi][ni] = mfma16(afh2[mi], bfl[ni], acc[4 + mi][ni]);
#pragma unroll
        for (int mi = 0; mi < 4; ++mi)
#pragma unroll
            for (int ni = 0; ni < 4; ++ni)
                acc[4 + mi][ni] = mfma16(afl2[mi], bfh[ni], acc[4 + mi][ni]);
        __builtin_amdgcn_s_setprio(0);

        // Drain t+1 staging (issued a full step ago) and release buffers.
        asm volatile("s_waitcnt vmcnt(0)" ::: "memory");
        __builtin_amdgcn_s_barrier();
    }

    // Epilogue: C/D layout col=lane&15, row=quad*4+i.
    float* dst = (bx < 4) ? XZ : ((bx < 8) ? XR : OUT);
    const long nl = (long)(bx & 3) * 256 + wc * 64 + l15;
#pragma unroll
    for (int mi = 0; mi < 8; ++mi) {
        const long m = m0 + wr * 128 + mi * 16 + quad * 4;
#pragma unroll
        for (int ni = 0; ni < 4; ++ni) {
            float* p = dst + m * H_DIM + nl + ni * 16;
#pragma unroll
            for (int i = 0; i < 4; ++i)
                p[(long)i * H_DIM] = acc[mi][ni][i];
        }
    }
}

// ---------------------------------------------------------------------------
// Fallback fp32 GEMM (round 0)
// ---------------------------------------------------------------------------
#define BM 128
#define BN 128
#define BK 8
__global__ __launch_bounds__(256) void gemm_f32(
    const float* __restrict__ A, const float* __restrict__ B,
    float* __restrict__ C, int M, int N, int K)
{
    __shared__ float As[BK][BM];
    __shared__ float Bs[BK][BN];
    const int tid = threadIdx.x;
    const int bm = blockIdx.y * BM, bn = blockIdx.x * BN;
    const int tx = tid & 15, ty = tid >> 4;
    float acc[8][8];
#pragma unroll
    for (int i = 0; i < 8; i++)
#pragma unroll
        for (int j = 0; j < 8; j++) acc[i][j] = 0.f;
    const int a_row = tid >> 1, a_k = (tid & 1) * 4;
    const int b_row = tid >> 5, b_col = (tid & 31) * 4;
    const float* Aptr = A + (size_t)(bm + a_row) * K + a_k;
    const float* Bptr = B + (size_t)b_row * N + bn + b_col;
    for (int k0 = 0; k0 < K; k0 += BK) {
        float4 av = *(const float4*)(Aptr + k0);
        float4 bv = *(const float4*)(Bptr + (size_t)k0 * N);
        As[a_k + 0][a_row] = av.x; As[a_k + 1][a_row] = av.y;
        As[a_k + 2][a_row] = av.z; As[a_k + 3][a_row] = av.w;
        *(float4*)&Bs[b_row][b_col] = bv;
        __syncthreads();
#pragma unroll
        for (int kk = 0; kk < BK; kk++) {
            float4 a0 = *(const float4*)&As[kk][ty * 8];
            float4 a1 = *(const float4*)&As[kk][ty * 8 + 4];
            float4 b0 = *(const float4*)&Bs[kk][tx * 8];
            float4 b1 = *(const float4*)&Bs[kk][tx * 8 + 4];
            float a[8] = {a0.x, a0.y, a0.z, a0.w, a1.x, a1.y, a1.z, a1.w};
            float b[8] = {b0.x, b0.y, b0.z, b0.w, b1.x, b1.y, b1.z, b1.w};
#pragma unroll
            for (int i = 0; i < 8; i++)
#pragma unroll
                for (int j = 0; j < 8; j++)
                    acc[i][j] = fmaf(a[i], b[j], acc[i][j]);
        }
        __syncthreads();
    }
    float* Cptr = C + (size_t)(bm + ty * 8) * N + bn + tx * 8;
#pragma unroll
    for (int i = 0; i < 8; i++) {
        float4 c0 = {acc[i][0], acc[i][1], acc[i][2], acc[i][3]};
        float4 c1 = {acc[i][4], acc[i][5], acc[i][6], acc[i][7]};
        *(float4*)(Cptr + (size_t)i * N)     = c0;
        *(float4*)(Cptr + (size_t)i * N + 4) = c1;
    }
}

// ---------------------------------------------------------------------------
// Scan, 16-deep prefetch. OUT holds xh on entry, h_t on exit.
// All three gates in sigmoid form; divisions via v_rcp + 1 Newton step
// (<=1ulp ~ IEEE div); biases and 2x factors folded off the h-chain.
//   u1 = -2q  = hs*(-2mr) + (-2(xr+br));  s1 = 1/(1+e^u1) = sig(2q); r = 2*s1
//   uz = -p   = hs*(-mz)  + (-(xz+bz));   z  = 1/(1+e^uz)
//   u2 = -2y  = s1*(-4hs) + (-2*xh);      th = 2/(1+e^u2) - 1 = tanh(y)
//   hn = th + z*(hs - th)
// ---------------------------------------------------------------------------
__device__ __forceinline__ float vrcp_nr(float d) {
    float r = __builtin_amdgcn_rcpf(d);
    return r * fmaf(-d, r, 2.0f);     // Newton: r*(2 - d*r)
}

__global__ __launch_bounds__(256) void scan_kernel(
    const float* __restrict__ XZ, const float* __restrict__ XR,
    float* __restrict__ OUT,
    const float* __restrict__ mz, const float* __restrict__ mr,
    const float* __restrict__ br, const float* __restrict__ bz)
{
    const int gid = blockIdx.x * blockDim.x + threadIdx.x;
    const int b = gid >> 10;          // H=1024
    const int h = gid & (H_DIM - 1);

    const float mzK = -mz[h];
    const float mrK = -2.0f * mr[h];
    const float bzK = -bz[h];
    const float brK = -2.0f * br[h];
    float hs = 0.f;
    size_t idx = (size_t)b * 512 * H_DIM + h;

    float cz[16], cr[16], ch[16];
#pragma unroll
    for (int j = 0; j < 16; ++j) {
        cz[j] = bzK - XZ[idx + (size_t)j * H_DIM];
        cr[j] = fmaf(-2.0f, XR[idx + (size_t)j * H_DIM], brK);
        ch[j] = -2.0f * OUT[idx + (size_t)j * H_DIM];
    }
    for (int t0 = 0; t0 < 512; t0 += 16) {
        float nz[16], nr[16], nh[16];
        const bool more = (t0 + 16) < 512;
        const size_t nidx = idx + 16ul * H_DIM;
        if (more) {
#pragma unroll
            for (int j = 0; j < 16; ++j) {
                nz[j] = XZ[nidx + (size_t)j * H_DIM];
                nr[j] = XR[nidx + (size_t)j * H_DIM];
                nh[j] = OUT[nidx + (size_t)j * H_DIM];
            }
        }
#pragma unroll
        for (int j = 0; j < 16; ++j) {
            const float u1   = fmaf(hs, mrK, cr[j]);
            const float uz   = fmaf(hs, mzK, cz[j]);
            const float hsK2 = -4.0f * hs;
            const float e1 = __expf(u1);
            const float s1 = vrcp_nr(e1 + 1.0f);
            const float ez = __expf(uz);
            const float sz = vrcp_nr(ez + 1.0f);
            const float u2 = fmaf(s1, hsK2, ch[j]);
            const float e2 = __expf(u2);
            const float s2 = vrcp_nr(e2 + 1.0f);
            const float th = fmaf(2.0f, s2, -1.0f);
            const float hn = fmaf(sz, hs - th, th);
            OUT[idx + (size_t)j * H_DIM] = hn;
            hs = hn;
        }
        idx = nidx;
        if (more) {
#pragma unroll
            for (int j = 0; j < 16; ++j) {
                cz[j] = bzK - nz[j];
                cr[j] = fmaf(-2.0f, nr[j], brK);
                ch[j] = -2.0f * nh[j];
            }
        }
    }
}

// ---------------------------------------------------------------------------
extern "C" void kernel_launch(void* const* d_in, const int* in_sizes, int n_in,
                              void* d_out, int out_size, void* d_ws, size_t ws_size,
                              hipStream_t stream) {
    const float* x  = (const float*)d_in[0];
    const float* kz = (const float*)d_in[1];
    const float* kr = (const float*)d_in[2];
    const float* kh = (const float*)d_in[3];
    const float* mz = (const float*)d_in[4];
    const float* mr = (const float*)d_in[5];
    const float* br = (const float*)d_in[6];
    const float* bz = (const float*)d_in[7];
    float* out = (float*)d_out;

    char* ws = (char*)d_ws;
    float* XZ = (float*)ws;                              // 128 MiB
    float* XR = (float*)(ws + 134217728ul);              // 128 MiB
    _Float16* XHI = (_Float16*)(ws + 268435456ul);       // 32 MiB
    _Float16* XLO = (_Float16*)(ws + 301989888ul);       // 32 MiB
    _Float16* WTH = (_Float16*)(ws + 335544320ul);       // 3 MiB
    _Float16* WTL = (_Float16*)(ws + 338690048ul);       // 3 MiB
    const size_t need = 341835776ul;

    if (ws_size >= need) {
        int n4 = M_DIM * K_DIM / 4;                      // 4.19M
        convert_x<<<n4 / 256, 256, 0, stream>>>(
            (const float4*)x, (half4v*)XHI, (half4v*)XLO, n4);
        convert_wt<<<(3 * H_DIM * K_DIM) / 256, 256, 0, stream>>>(
            kz, kr, kh, WTH, WTL);
        gemm_mfma_split<<<1536, 512, 0, stream>>>(
            XHI, XLO, WTH, WTL, XZ, XR, out);
    } else {
        dim3 grid(H_DIM / BN, M_DIM / BM);
        gemm_f32<<<grid, 256, 0, stream>>>(x, kz, XZ,  M_DIM, H_DIM, K_DIM);
        gemm_f32<<<grid, 256, 0, stream>>>(x, kr, XR,  M_DIM, H_DIM, K_DIM);
        gemm_f32<<<grid, 256, 0, stream>>>(x, kh, out, M_DIM, H_DIM, K_DIM);
    }

    scan_kernel<<<(64 * H_DIM) / 256, 256, 0, stream>>>(
        XZ, XR, out, mz, mr, br, bz);
}